// Round 1
// baseline (4037.304 us; speedup 1.0000x reference)
//
#include <hip/hip_runtime.h>
#include <hip/hip_bf16.h>
#include <cstddef>

// Problem dims (fixed by the reference)
constexpr int B = 32, T = 128, S = 128, D = 512, H = 512, V = 16000;
constexpr int G4H = 4 * H;     // 2048
constexpr int TB = T * B;      // 4096

__device__ __forceinline__ float tanh_fast(float x) {
    // tanh(x) = 1 - 2/(exp(2x)+1); saturates correctly at +-inf
    return 1.0f - 2.0f / (__expf(2.0f * x) + 1.0f);
}
__device__ __forceinline__ float sigmoid_fast(float x) {
    return 1.0f / (1.0f + __expf(-x));
}

// ---------------------------------------------------------------------------
// Embedding gather: emb_g[t*B+b][:] = embed[tok(t,b)][:]
// tok(t,b) = x[b,0] if t==0 else teacher[b,t-1]
// ---------------------------------------------------------------------------
__global__ __launch_bounds__(128) void gather_emb(
    const int* __restrict__ x, const int* __restrict__ teacher,
    const float* __restrict__ embed, float* __restrict__ emb_g)
{
    int r = blockIdx.x;            // t*B + b
    int t = r >> 5, b = r & 31;
    int tok = (t == 0) ? x[b * T] : teacher[b * T + t - 1];
    const float4* src = (const float4*)(embed + (size_t)tok * D);
    float4* dst = (float4*)(emb_g + (size_t)r * D);
    dst[threadIdx.x] = src[threadIdx.x];   // 128 threads * float4 = 512 floats
}

// ---------------------------------------------------------------------------
// Generic fp32 tiled GEMM.
//   BT=true : C[M][N] = A[M][K] * B[N][K]^T        (B row-major [N][K])
//   BT=false: C[M][N] = A[M][K] * B[K][N]          (B row-major [K][N])
// bias1/bias2 (optional, per-column) added in epilogue.
// REMAP=true: output row r=t*B+b is written to C[(b*T+t)*N + col]  (for d_out)
// BM=128, BN=64, BK=16, 256 threads, thread tile 8x4.
// ---------------------------------------------------------------------------
template<bool BT, bool REMAP>
__global__ __launch_bounds__(256) void gemm_kernel(
    const float* __restrict__ A, const float* __restrict__ Bm,
    const float* __restrict__ bias1, const float* __restrict__ bias2,
    float* __restrict__ C, int M, int N, int K)
{
    constexpr int BM = 128, BN = 64, BK = 16;
    __shared__ float As[BK][BM + 4];
    __shared__ float Bs[BK][BN + 4];

    int tid = threadIdx.x;
    int m0 = blockIdx.y * BM, n0 = blockIdx.x * BN;
    int tx = tid & 15, ty = tid >> 4;

    // A-load mapping: 128x16 tile = 512 float4; 2 per thread
    int ar = tid >> 2;            // 0..63
    int ak = (tid & 3) * 4;       // 0,4,8,12
    // B-load (BT=false) mapping: 16x64 tile = 256 float4; 1 per thread
    int bkk = tid >> 4;           // 0..15
    int bnn = (tid & 15) * 4;     // 0..60

    float acc[8][4];
    #pragma unroll
    for (int i = 0; i < 8; ++i)
        #pragma unroll
        for (int j = 0; j < 4; ++j) acc[i][j] = 0.f;

    for (int k0 = 0; k0 < K; k0 += BK) {
        #pragma unroll
        for (int rr = 0; rr < 2; ++rr) {
            int row = ar + rr * 64;
            float4 v = *(const float4*)(A + (size_t)(m0 + row) * K + k0 + ak);
            As[ak + 0][row] = v.x; As[ak + 1][row] = v.y;
            As[ak + 2][row] = v.z; As[ak + 3][row] = v.w;
        }
        if (BT) {
            float4 v = *(const float4*)(Bm + (size_t)(n0 + ar) * K + k0 + ak);
            Bs[ak + 0][ar] = v.x; Bs[ak + 1][ar] = v.y;
            Bs[ak + 2][ar] = v.z; Bs[ak + 3][ar] = v.w;
        } else {
            float4 v = *(const float4*)(Bm + (size_t)(k0 + bkk) * N + n0 + bnn);
            *(float4*)&Bs[bkk][bnn] = v;
        }
        __syncthreads();

        #pragma unroll
        for (int kk = 0; kk < BK; ++kk) {
            float a[8], bb[4];
            *(float4*)&a[0] = *(const float4*)&As[kk][ty * 8];
            *(float4*)&a[4] = *(const float4*)&As[kk][ty * 8 + 4];
            *(float4*)&bb[0] = *(const float4*)&Bs[kk][tx * 4];
            #pragma unroll
            for (int i = 0; i < 8; ++i)
                #pragma unroll
                for (int j = 0; j < 4; ++j)
                    acc[i][j] = fmaf(a[i], bb[j], acc[i][j]);
        }
        __syncthreads();
    }

    float bs[4];
    #pragma unroll
    for (int j = 0; j < 4; ++j) {
        float v = 0.f;
        if (bias1) v += bias1[n0 + tx * 4 + j];
        if (bias2) v += bias2[n0 + tx * 4 + j];
        bs[j] = v;
    }
    #pragma unroll
    for (int i = 0; i < 8; ++i) {
        int row = m0 + ty * 8 + i;
        float* crow;
        if (REMAP) {
            int t = row >> 5, b = row & 31;           // row = t*B+b
            crow = C + ((size_t)b * T + t) * N;
        } else {
            crow = C + (size_t)row * N;
        }
        float4 o;
        o.x = acc[i][0] + bs[0]; o.y = acc[i][1] + bs[1];
        o.z = acc[i][2] + bs[2]; o.w = acc[i][3] + bs[3];
        *(float4*)(crow + n0 + tx * 4) = o;
    }
}

// ---------------------------------------------------------------------------
// One LSTM step. hx stored transposed [H][B] for coalescing; double-buffered.
// Grid: 512 blocks (one per h), 128 threads = 32 b x 4 gates.
// gates_ih_t: [B][4H] slice for this step (biases already included).
// Writes hx_out [H][B], cx [H][B] (in/out), and Hseq slice [B][H].
// ---------------------------------------------------------------------------
__global__ __launch_bounds__(128) void lstm_step(
    const float* __restrict__ gates_ih_t, const float* __restrict__ W_hh,
    const float* __restrict__ hx_in, float* __restrict__ hx_out,
    float* __restrict__ cx, float* __restrict__ hseq_t)
{
    int h = blockIdx.x;
    int tid = threadIdx.x;
    int b = tid & 31, g = tid >> 5;
    int row = g * H + h;
    const float* w = W_hh + (size_t)row * H;

    float acc0 = 0.f, acc1 = 0.f, acc2 = 0.f, acc3 = 0.f;
    #pragma unroll 8
    for (int k = 0; k < H; k += 4) {
        float4 wv = *(const float4*)&w[k];
        float x0 = hx_in[(k + 0) * B + b];
        float x1 = hx_in[(k + 1) * B + b];
        float x2 = hx_in[(k + 2) * B + b];
        float x3 = hx_in[(k + 3) * B + b];
        acc0 = fmaf(x0, wv.x, acc0);
        acc1 = fmaf(x1, wv.y, acc1);
        acc2 = fmaf(x2, wv.z, acc2);
        acc3 = fmaf(x3, wv.w, acc3);
    }
    float gate = acc0 + acc1 + acc2 + acc3 + gates_ih_t[(size_t)b * G4H + row];

    __shared__ float gl[4][32];
    gl[g][b] = gate;
    __syncthreads();

    if (tid < 32) {
        int bb = tid;
        float gi = gl[0][bb], gf = gl[1][bb], gg = gl[2][bb], go = gl[3][bb];
        float i = sigmoid_fast(gi);
        float f = sigmoid_fast(gf);
        float o = sigmoid_fast(go);
        float c_old = cx[h * B + bb];
        float c_new = fmaf(f, c_old, i * tanh_fast(gg));
        float h_new = o * tanh_fast(c_new);
        cx[h * B + bb] = c_new;
        hx_out[h * B + bb] = h_new;
        hseq_t[(size_t)bb * H + h] = h_new;
    }
}

// ---------------------------------------------------------------------------
// Fused attention (batched over all (t,b)): score -> softmax -> context -> U.
// Block per row r=t*B+b, 256 threads.
// U[r] = [cxt(512) | hx(512)]
// ---------------------------------------------------------------------------
__global__ __launch_bounds__(256) void attn_fused(
    const float* __restrict__ Q, const float* __restrict__ keys,
    const float* __restrict__ z, const float* __restrict__ v_att,
    const float* __restrict__ Hseq, float* __restrict__ U)
{
    __shared__ float qv[512], va[512], ph[256], sc[128], red[128];
    int r = blockIdx.x, b = r & 31, tid = threadIdx.x;

    if (tid < 128) ((float4*)qv)[tid] = ((const float4*)(Q + (size_t)r * H))[tid];
    else           ((float4*)va)[tid - 128] = ((const float4*)v_att)[tid - 128];
    __syncthreads();

    // scores: 2 threads per s (each half of h)
    int s = tid >> 1, half = tid & 1;
    const float4* k4 = (const float4*)(keys + ((size_t)b * S + s) * H + half * 256);
    const float4* q4p = (const float4*)(qv + half * 256);
    const float4* v4p = (const float4*)(va + half * 256);
    float acc = 0.f;
    #pragma unroll 4
    for (int i = 0; i < 64; ++i) {
        float4 kv = k4[i], q4 = q4p[i], v4 = v4p[i];
        acc += tanh_fast(kv.x + q4.x) * v4.x + tanh_fast(kv.y + q4.y) * v4.y
             + tanh_fast(kv.z + q4.z) * v4.z + tanh_fast(kv.w + q4.w) * v4.w;
    }
    ph[tid] = acc;
    __syncthreads();
    if (tid < 128) { float v = ph[2 * tid] + ph[2 * tid + 1]; sc[tid] = v; red[tid] = v; }
    __syncthreads();
    for (int st = 64; st > 0; st >>= 1) {
        if (tid < st) red[tid] = fmaxf(red[tid], red[tid + st]);
        __syncthreads();
    }
    float mx = red[0];
    __syncthreads();
    if (tid < 128) { float e = __expf(sc[tid] - mx); sc[tid] = e; red[tid] = e; }
    __syncthreads();
    for (int st = 64; st > 0; st >>= 1) {
        if (tid < st) red[tid] += red[tid + st];
        __syncthreads();
    }
    float inv = 1.0f / red[0];

    // context: 2 h per thread
    const float* zb = z + (size_t)b * S * H;
    int h1 = tid, h2 = tid + 256;
    float c1 = 0.f, c2 = 0.f;
    #pragma unroll 4
    for (int s2 = 0; s2 < S; ++s2) {
        float wgt = sc[s2];
        c1 = fmaf(wgt, zb[(size_t)s2 * H + h1], c1);
        c2 = fmaf(wgt, zb[(size_t)s2 * H + h2], c2);
    }
    float* urow = U + (size_t)r * (2 * H);
    urow[h1] = c1 * inv;
    urow[h2] = c2 * inv;
    urow[H + h1] = Hseq[(size_t)r * H + h1];
    urow[H + h2] = Hseq[(size_t)r * H + h2];
}

// ---------------------------------------------------------------------------
extern "C" void kernel_launch(void* const* d_in, const int* in_sizes, int n_in,
                              void* d_out, int out_size, void* d_ws, size_t ws_size,
                              hipStream_t stream)
{
    const int*   x       = (const int*)  d_in[0];
    const int*   teacher = (const int*)  d_in[1];
    const float* z       = (const float*)d_in[2];
    const float* embed   = (const float*)d_in[3];
    const float* W_ih    = (const float*)d_in[4];
    const float* b_ih    = (const float*)d_in[5];
    const float* W_hh    = (const float*)d_in[6];
    const float* b_hh    = (const float*)d_in[7];
    const float* Wq      = (const float*)d_in[8];
    const float* Wk      = (const float*)d_in[9];
    const float* v_att   = (const float*)d_in[10];
    const float* W_proj  = (const float*)d_in[11];
    const float* b_proj  = (const float*)d_in[12];
    float* out = (float*)d_out;

    // workspace layout (floats)
    float* ws = (float*)d_ws;
    float* emb_g    = ws;                       // TB*D       = 2M
    float* gates_ih = emb_g + (size_t)TB * D;   // TB*4H      = 8M
    float* keys     = gates_ih + (size_t)TB * G4H; // TB*H    = 2M (B*S*H)
    float* hbuf0    = keys + (size_t)B * S * H; // H*B
    float* hbuf1    = hbuf0 + H * B;
    float* cxbuf    = hbuf1 + H * B;
    float* Hseq     = cxbuf + H * B;            // TB*H
    float* Qbuf     = Hseq + (size_t)TB * H;    // TB*H
    float* Ubuf     = Qbuf + (size_t)TB * H;    // TB*2H

    hipMemsetAsync(hbuf0, 0, H * B * sizeof(float), stream);
    hipMemsetAsync(cxbuf, 0, H * B * sizeof(float), stream);

    gather_emb<<<TB, 128, 0, stream>>>(x, teacher, embed, emb_g);

    // gates_ih = emb_g @ W_ih^T + (b_ih + b_hh)
    gemm_kernel<true, false><<<dim3(G4H / 64, TB / 128), 256, 0, stream>>>(
        emb_g, W_ih, b_ih, b_hh, gates_ih, TB, G4H, D);

    // keys = z @ Wk   (non-transposed B)
    gemm_kernel<false, false><<<dim3(H / 64, TB / 128), 256, 0, stream>>>(
        z, Wk, nullptr, nullptr, keys, B * S, H, H);

    // sequential LSTM recurrence
    for (int t = 0; t < T; ++t) {
        const float* hin = (t & 1) ? hbuf1 : hbuf0;
        float* hout      = (t & 1) ? hbuf0 : hbuf1;
        lstm_step<<<H, 128, 0, stream>>>(
            gates_ih + (size_t)t * B * G4H, W_hh, hin, hout, cxbuf,
            Hseq + (size_t)t * B * H);
    }

    // Q = Hseq @ Wq^T
    gemm_kernel<true, false><<<dim3(H / 64, TB / 128), 256, 0, stream>>>(
        Hseq, Wq, nullptr, nullptr, Qbuf, TB, H, H);

    // attention fused: scores+softmax+context+U
    attn_fused<<<TB, 256, 0, stream>>>(Qbuf, keys, z, v_att, Hseq, Ubuf);

    // logits = U @ W_proj^T + b_proj, written directly in [B,T,V] order
    gemm_kernel<true, true><<<dim3(V / 64, TB / 128), 256, 0, stream>>>(
        Ubuf, W_proj, b_proj, nullptr, out, TB, V, 1024);
}